// Round 11
// baseline (635.510 us; speedup 1.0000x reference)
//
#include <hip/hip_runtime.h>
#include <math.h>

// ============================================================================
// R11: fix pv traffic + latency (R10 went BW-bound: 408MB fetch, half-line
// loads; R9/R10 balance experiments regressed vs R8's simple grid).
// * pv_k: R8 grid (8,32,2), unique Y tile/block (no atomics/slots/zero),
//   64-s chunks -> every staged row = one full 128B cache line, 128 MFMA per
//   barrier-pair; P precomputed (pbuild); register prefetch of next chunk;
//   Ps/Vs padded [64][72] (2-way LDS aliasing = free).
// * Qcat/Kcat interleaved [hi32|lo32] per 32-k chunk -> scores_k staging is
//   full-line too; scores_k gets register prefetch of next K-chunk.
// Numerics identical to R8-R10 (absmax 0.015625 expected).
// ============================================================================

#define B_ 2
#define T_ 2048
#define C_ 512
#define NB_ 4
#define C2_ 1024  // interleaved row width for Qcat/Kcat

typedef unsigned short u16;
typedef unsigned char u8;
using short8 = __attribute__((ext_vector_type(8))) short;
using bf16x8 = __attribute__((ext_vector_type(8))) __bf16;
using f32x4  = __attribute__((ext_vector_type(4))) float;

__device__ __forceinline__ float bf2f(u16 u) {
  union { unsigned int i; float f; } v; v.i = ((unsigned int)u) << 16; return v.f;
}
__device__ __forceinline__ u16 f2bf(float f) {  // round-to-nearest-even
  union { float f; unsigned int i; } v; v.f = f;
  unsigned int u = v.i;
  return (u16)((u + 0x7fffu + ((u >> 16) & 1u)) >> 16);
}
__device__ __forceinline__ f32x4 mfma16x16x32(short8 a, short8 b, f32x4 c) {
  return __builtin_amdgcn_mfma_f32_16x16x32_bf16(
      __builtin_bit_cast(bf16x8, a), __builtin_bit_cast(bf16x8, b), c, 0, 0, 0);
}
__device__ __forceinline__ void split8(const float* s, uint4& hi, uint4& lo) {
  u16 h[8], l[8];
#pragma unroll
  for (int j = 0; j < 8; ++j) {
    h[j] = f2bf(s[j]);
    l[j] = f2bf(s[j] - bf2f(h[j]));
  }
  hi.x = h[0] | ((unsigned)h[1] << 16); hi.y = h[2] | ((unsigned)h[3] << 16);
  hi.z = h[4] | ((unsigned)h[5] << 16); hi.w = h[6] | ((unsigned)h[7] << 16);
  lo.x = l[0] | ((unsigned)l[1] << 16); lo.y = l[2] | ((unsigned)l[3] << 16);
  lo.z = l[4] | ((unsigned)l[5] << 16); lo.w = l[6] | ((unsigned)l[7] << 16);
}

// ---------------------------------------------------------------------------
// Split-precision 64x64 GEMM with fused RoPE epilogue.
// Output layout (interleaved): row of C2_=1024 u16, k-chunk c5=k>>5:
//   hi at c5*64 + (k&31), lo at c5*64 + 32 + (k&31).
// MODE 1: +1/sqrt(C) scale -> Qcat (B,NB,T,rows). MODE 2: -> Kcat (B*T,rows).
// ---------------------------------------------------------------------------
template <int MODE>
__global__ __launch_bounds__(256) void gemm_qk(const float* __restrict__ A,
                                               const float* __restrict__ W,
                                               u16* __restrict__ out,
                                               const float* __restrict__ cosT,
                                               const float* __restrict__ sinT,
                                               const int N, const int K) {
  __shared__ u16 Ah[64][32], Al[64][32];
  __shared__ u16 Bh[64][32], Bl[64][32];  // [n][k]
  const int tid = threadIdx.x;
  const int wave = tid >> 6, lane = tid & 63;
  const int m0 = blockIdx.y << 6, n0 = blockIdx.x << 6;
  const f32x4 zero = {0.f, 0.f, 0.f, 0.f};
  f32x4 acc[4] = {zero, zero, zero, zero};
  const int srow = tid >> 2, koff = (tid & 3) << 3;  // linear LDS staging
  const int lrow = lane & 15, lk = (lane >> 4) << 3;
  for (int kk = 0; kk < K; kk += 32) {
    float av[8];
    *(float4*)(av) = *(const float4*)(&A[(size_t)(m0 + srow) * K + kk + koff]);
    *(float4*)(av + 4) =
        *(const float4*)(&A[(size_t)(m0 + srow) * K + kk + koff + 4]);
    uint4 hi, lo;
    split8(av, hi, lo);
    *(uint4*)(&Ah[srow][koff]) = hi;
    *(uint4*)(&Al[srow][koff]) = lo;
    float wv[8];
#pragma unroll
    for (int j = 0; j < 8; ++j)
      wv[j] = W[(size_t)(kk + koff + j) * N + n0 + srow];
    split8(wv, hi, lo);
    *(uint4*)(&Bh[srow][koff]) = hi;
    *(uint4*)(&Bl[srow][koff]) = lo;
    __syncthreads();
    short8 ah = *(const short8*)(&Ah[(wave << 4) + lrow][lk]);
    short8 al = *(const short8*)(&Al[(wave << 4) + lrow][lk]);
#pragma unroll
    for (int ns = 0; ns < 4; ++ns) {
      short8 bh = *(const short8*)(&Bh[(ns << 4) + lrow][lk]);
      short8 bl = *(const short8*)(&Bl[(ns << 4) + lrow][lk]);
      acc[ns] = mfma16x16x32(ah, bh, acc[ns]);
      acc[ns] = mfma16x16x32(al, bh, acc[ns]);
      acc[ns] = mfma16x16x32(ah, bl, acc[ns]);
    }
    __syncthreads();
  }
  const int r0 = m0 + (wave << 4) + ((lane >> 4) << 2);
  const int cb = n0 + (lane & 15);
#pragma unroll
  for (int ns = 0; ns < 4; ++ns) {
#pragma unroll
    for (int r = 0; r < 4; ++r) {
      const int rg = r0 + r;
      const int cg = cb + (ns << 4);
      float v = acc[ns][r];
      float pv = __shfl_xor(v, 1);  // partner column of the RoPE pair
      const int t = rg & (T_ - 1);
      const int c = (MODE == 1) ? (cg & (C_ - 1)) : cg;
      const int i = c >> 1;
      const float cf = cosT[(t << 8) + i];
      const float sf = sinT[(t << 8) + i];
      float x1 = (lane & 1) ? pv : v;
      float x2 = (lane & 1) ? v : pv;
      float y = (lane & 1) ? (x1 * sf + x2 * cf) : (x1 * cf - x2 * sf);
      if (MODE == 1) y *= 0.044194173824159216f;  // 1/sqrt(512)
      const u16 hi = f2bf(y);
      const u16 lo = f2bf(y - bf2f(hi));
      size_t rowoff;
      if (MODE == 1) {
        const int b = rg >> 11, n = cg >> 9;
        rowoff = ((size_t)((b * NB_ + n) * T_ + t)) * C2_;
      } else {
        rowoff = (size_t)rg * C2_;
      }
      const int ipos = ((c >> 5) << 6) + (c & 31);  // interleaved
      out[rowoff + ipos] = hi;
      out[rowoff + ipos + 32] = lo;
    }
  }
}

// ---------------------------------------------------------------------------
// Plain hi-only GEMM: A f32 (AF32=1) or bf16, W f32; out bf16 or f32 (OF32).
// ---------------------------------------------------------------------------
template <int AF32, int OF32>
__global__ __launch_bounds__(256) void gemm_hi(const void* __restrict__ Ap,
                                               const float* __restrict__ W,
                                               void* __restrict__ outp,
                                               const int N, const int K) {
  __shared__ u16 As[64][32];
  __shared__ u16 Bs[64][32];
  const int tid = threadIdx.x;
  const int wave = tid >> 6, lane = tid & 63;
  const int m0 = blockIdx.y << 6, n0 = blockIdx.x << 6;
  const f32x4 zero = {0.f, 0.f, 0.f, 0.f};
  f32x4 acc[4] = {zero, zero, zero, zero};
  const int srow = tid >> 2, koff = (tid & 3) << 3;  // linear LDS staging
  const int lrow = lane & 15, lk = (lane >> 4) << 3;
  for (int kk = 0; kk < K; kk += 32) {
    if (AF32) {
      const float* A = (const float*)Ap;
      float av[8];
      *(float4*)(av) = *(const float4*)(&A[(size_t)(m0 + srow) * K + kk + koff]);
      *(float4*)(av + 4) =
          *(const float4*)(&A[(size_t)(m0 + srow) * K + kk + koff + 4]);
      uint4 hi;
      hi.x = f2bf(av[0]) | ((unsigned)f2bf(av[1]) << 16);
      hi.y = f2bf(av[2]) | ((unsigned)f2bf(av[3]) << 16);
      hi.z = f2bf(av[4]) | ((unsigned)f2bf(av[5]) << 16);
      hi.w = f2bf(av[6]) | ((unsigned)f2bf(av[7]) << 16);
      *(uint4*)(&As[srow][koff]) = hi;
    } else {
      const u16* A = (const u16*)Ap;
      *(uint4*)(&As[srow][koff]) =
          *(const uint4*)(&A[(size_t)(m0 + srow) * K + kk + koff]);
    }
    uint4 hi;
    {
      float w[8];
#pragma unroll
      for (int j = 0; j < 8; ++j)
        w[j] = W[(size_t)(kk + koff + j) * N + n0 + srow];
      hi.x = f2bf(w[0]) | ((unsigned)f2bf(w[1]) << 16);
      hi.y = f2bf(w[2]) | ((unsigned)f2bf(w[3]) << 16);
      hi.z = f2bf(w[4]) | ((unsigned)f2bf(w[5]) << 16);
      hi.w = f2bf(w[6]) | ((unsigned)f2bf(w[7]) << 16);
    }
    *(uint4*)(&Bs[srow][koff]) = hi;
    __syncthreads();
    short8 af = *(const short8*)(&As[(wave << 4) + lrow][lk]);
#pragma unroll
    for (int ns = 0; ns < 4; ++ns) {
      short8 bf = *(const short8*)(&Bs[(ns << 4) + lrow][lk]);
      acc[ns] = mfma16x16x32(af, bf, acc[ns]);
    }
    __syncthreads();
  }
  const int r0 = m0 + (wave << 4) + ((lane >> 4) << 2);
  const int cb = n0 + (lane & 15);
#pragma unroll
  for (int ns = 0; ns < 4; ++ns) {
#pragma unroll
    for (int r = 0; r < 4; ++r) {
      const size_t idx = (size_t)(r0 + r) * N + cb + (ns << 4);
      if (OF32) ((float*)outp)[idx] = acc[ns][r];
      else ((u16*)outp)[idx] = f2bf(acc[ns][r]);
    }
  }
}

// ---------------------------------------------------------------------------
// Vraw (B,T,NB*C) bf16 -> VT (B,NB,C,T) tiled transpose, 64x64 tiles.
// ---------------------------------------------------------------------------
__global__ __launch_bounds__(256) void transpose_v_k(const u16* __restrict__ Vraw,
                                                     u16* __restrict__ VT) {
  const int bid = blockIdx.x;
  const int ct = bid & 7;
  const int ttile = (bid >> 3) & 31;
  const int n = (bid >> 8) & 3;
  const int b = bid >> 10;
  __shared__ u16 tile[64][68];
  const int tid = threadIdx.x;
  const int rr = tid >> 4;
  const int cc = (tid & 15) << 2;
  const int t0 = ttile << 6, c0 = ct << 6;
#pragma unroll
  for (int it = 0; it < 4; ++it) {
    const int r = (it << 4) + rr;
    *(ushort4*)(&tile[r][cc]) = *(const ushort4*)(
        &Vraw[((size_t)((b << 11) + t0 + r)) * (NB_ * C_) + n * C_ + c0 + cc]);
  }
  __syncthreads();
#pragma unroll
  for (int it = 0; it < 4; ++it) {
    const int c = (it << 4) + rr;
    ushort4 w;
    w.x = tile[cc + 0][c]; w.y = tile[cc + 1][c];
    w.z = tile[cc + 2][c]; w.w = tile[cc + 3][c];
    *(ushort4*)(&VT[((size_t)((b * NB_ + n) * C_ + c0 + c)) * T_ + t0 + cc]) = w;
  }
}

// ---------------------------------------------------------------------------
// Scores: per lower-tri 64x64 (t,s) tile (triangular grid), 4 branches,
// fused split segments (40KB LDS). Interleaved Qcat/Kcat -> full-128B-line
// staging (8 threads/row, 2 passes) + register prefetch of next K-chunk.
// ---------------------------------------------------------------------------
__global__ __launch_bounds__(256) void scores_k(const u16* __restrict__ Qcat,
                                                const u16* __restrict__ Kcat,
                                                u16* __restrict__ Mout,
                                                u8* __restrict__ Mask) {
  const int tri = blockIdx.x;
  int tt = (int)((sqrtf(8.f * (float)tri + 1.f) - 1.f) * 0.5f);
  while ((tt + 1) * (tt + 2) / 2 <= tri) ++tt;
  while (tt * (tt + 1) / 2 > tri) --tt;
  const int ss = tri - tt * (tt + 1) / 2;
  const int b = blockIdx.y;
  __shared__ u16 Qh[NB_][64][32], Ql[NB_][64][32];
  __shared__ u16 Kh[64][32], Kl[64][32];
  const int tid = threadIdx.x;
  const int wave = tid >> 6, lane = tid & 63;
  const int t0 = tt << 6, s0 = ss << 6;
  const f32x4 zero = {0.f, 0.f, 0.f, 0.f};
  f32x4 acc[NB_][4];
  for (int n = 0; n < NB_; ++n)
    for (int j = 0; j < 4; ++j) acc[n][j] = zero;
  const int row0 = tid >> 3, part = tid & 7;  // 8 threads cover a 128B row
  const int p3 = (part & 3) << 3;             // col within hi/lo half
  const int lrow = lane & 15, lk = (lane >> 4) << 3;

  uint4 qv[NB_][2], kv[2];
  // prefetch chunk 0
#pragma unroll
  for (int ps = 0; ps < 2; ++ps) {
    const int r = row0 + (ps << 5);
#pragma unroll
    for (int n = 0; n < NB_; ++n)
      qv[n][ps] = *(const uint4*)(
          &Qcat[((size_t)((b * NB_ + n) * T_ + t0 + r)) * C2_ + (part << 3)]);
    kv[ps] = *(const uint4*)(
        &Kcat[((size_t)((b << 11) + s0 + r)) * C2_ + (part << 3)]);
  }
  for (int c5 = 0; c5 < 16; ++c5) {
#pragma unroll
    for (int ps = 0; ps < 2; ++ps) {
      const int r = row0 + (ps << 5);
#pragma unroll
      for (int n = 0; n < NB_; ++n) {
        u16* dst = (part < 4) ? &Qh[n][r][p3] : &Ql[n][r][p3];
        *(uint4*)dst = qv[n][ps];
      }
      u16* dstk = (part < 4) ? &Kh[r][p3] : &Kl[r][p3];
      *(uint4*)dstk = kv[ps];
    }
    __syncthreads();
    if (c5 < 15) {  // prefetch next chunk (overlaps MFMA)
      const int off = ((c5 + 1) << 6) + (part << 3);
#pragma unroll
      for (int ps = 0; ps < 2; ++ps) {
        const int r = row0 + (ps << 5);
#pragma unroll
        for (int n = 0; n < NB_; ++n)
          qv[n][ps] = *(const uint4*)(
              &Qcat[((size_t)((b * NB_ + n) * T_ + t0 + r)) * C2_ + off]);
        kv[ps] = *(const uint4*)(
            &Kcat[((size_t)((b << 11) + s0 + r)) * C2_ + off]);
      }
    }
    short8 qhf[NB_], qlf[NB_];
#pragma unroll
    for (int n = 0; n < NB_; ++n) {
      qhf[n] = *(const short8*)(&Qh[n][(wave << 4) + lrow][lk]);
      qlf[n] = *(const short8*)(&Ql[n][(wave << 4) + lrow][lk]);
    }
#pragma unroll
    for (int ns = 0; ns < 4; ++ns) {
      short8 khf = *(const short8*)(&Kh[(ns << 4) + lrow][lk]);
      short8 klf = *(const short8*)(&Kl[(ns << 4) + lrow][lk]);
#pragma unroll
      for (int n = 0; n < NB_; ++n) {
        acc[n][ns] = mfma16x16x32(qhf[n], khf, acc[n][ns]);
        acc[n][ns] = mfma16x16x32(qlf[n], khf, acc[n][ns]);
        acc[n][ns] = mfma16x16x32(qhf[n], klf, acc[n][ns]);
      }
    }
    __syncthreads();
  }
  const int tb = t0 + (wave << 4) + ((lane >> 4) << 2);
  const int sb = s0 + (lane & 15);
#pragma unroll
  for (int ns = 0; ns < 4; ++ns) {
#pragma unroll
    for (int r = 0; r < 4; ++r) {
      const int t = tb + r, s = sb + (ns << 4);
      float a0 = acc[0][ns][r], a1 = acc[1][ns][r];
      float a2 = acc[2][ns][r], a3 = acc[3][ns][r];
      float m = fmaxf(fmaxf(a0, a1), fmaxf(a2, a3));
      u8 msk = (u8)((a0 == m) | ((a1 == m) << 1) | ((a2 == m) << 2) |
                    ((a3 == m) << 3));
      if (s > t) { m = -__builtin_inff(); msk = 0; }
      const size_t idx = (size_t)b * T_ * T_ + (size_t)t * T_ + s;
      Mout[idx] = f2bf(m);
      Mask[idx] = msk;
    }
  }
}

// ---------------------------------------------------------------------------
// Per-row softmax stats from bf16 M: rowmax, 1/sum(exp). One wave per (b,t).
// ---------------------------------------------------------------------------
__global__ __launch_bounds__(256) void rowstats_k(const u16* __restrict__ Mb,
                                                  float* __restrict__ Rm,
                                                  float* __restrict__ Rz) {
  const int r = (blockIdx.x << 2) + (threadIdx.x >> 6);
  const int lane = threadIdx.x & 63;
  const int b = r >> 11, t = r & (T_ - 1);
  const u16* row = Mb + (size_t)b * T_ * T_ + (size_t)t * T_;
  float m = -__builtin_inff();
  for (int s = lane; s <= t; s += 64) m = fmaxf(m, bf2f(row[s]));
#pragma unroll
  for (int off = 32; off; off >>= 1) m = fmaxf(m, __shfl_xor(m, off));
  float z = 0.f;
  for (int s = lane; s <= t; s += 64) z += expf(bf2f(row[s]) - m);
#pragma unroll
  for (int off = 32; off; off >>= 1) z += __shfl_xor(z, off);
  if (lane == 0) { Rm[r] = m; Rz[r] = 1.f / z; }
}

// ---------------------------------------------------------------------------
// P-build: P[b,t,s] = f2bf(exp(M - rm) * rz). One block per (b,t) row.
// ---------------------------------------------------------------------------
__global__ __launch_bounds__(256) void pbuild_k(const u16* __restrict__ Mb,
                                                const float* __restrict__ Rm,
                                                const float* __restrict__ Rz,
                                                u16* __restrict__ Pb) {
  const int r = blockIdx.x;
  const float rm = Rm[r], rz = Rz[r];
  const size_t off = ((size_t)r << 11) + (threadIdx.x << 3);
  ushort4 m0 = *(const ushort4*)(&Mb[off]);
  ushort4 m1 = *(const ushort4*)(&Mb[off + 4]);
  u16 o[8];
  o[0] = f2bf(expf(bf2f(m0.x) - rm) * rz);
  o[1] = f2bf(expf(bf2f(m0.y) - rm) * rz);
  o[2] = f2bf(expf(bf2f(m0.z) - rm) * rz);
  o[3] = f2bf(expf(bf2f(m0.w) - rm) * rz);
  o[4] = f2bf(expf(bf2f(m1.x) - rm) * rz);
  o[5] = f2bf(expf(bf2f(m1.y) - rm) * rz);
  o[6] = f2bf(expf(bf2f(m1.z) - rm) * rz);
  o[7] = f2bf(expf(bf2f(m1.w) - rm) * rz);
  uint4 w;
  w.x = o[0] | ((unsigned)o[1] << 16); w.y = o[2] | ((unsigned)o[3] << 16);
  w.z = o[4] | ((unsigned)o[5] << 16); w.w = o[6] | ((unsigned)o[7] << 16);
  *(uint4*)(&Pb[off]) = w;
}

// ---------------------------------------------------------------------------
// Routed PV: grid (8 cblk, 32 tt, 2 b); each block owns the 64t x 64c tile
// uniquely. 64-s chunks: each staged row = 128B = one full cache line
// (8 threads/row, 2 passes). P precomputed; register prefetch of next chunk.
// LDS [64][72] padding: 144B row stride -> 2-way read aliasing (free).
// ---------------------------------------------------------------------------
__global__ __launch_bounds__(256) void pv_k(const u16* __restrict__ Pb,
                                            const u8* __restrict__ Mask,
                                            const u16* __restrict__ VT,
                                            u16* __restrict__ Y) {
  const int cblk = blockIdx.x, tt = blockIdx.y, b = blockIdx.z;
  const int t0 = tt << 6, c0 = cblk << 6;
  __shared__ u16 Ps[NB_][64][72];
  __shared__ u16 Vs[NB_][64][72];
  const int tid = threadIdx.x;
  const int wave = tid >> 6, lane = tid & 63;
  const int row0 = tid >> 3, part = tid & 7;  // 8 threads per 128B row
  const int lrow = lane & 15, lk = (lane >> 4) << 3;
  const f32x4 zero = {0.f, 0.f, 0.f, 0.f};
  f32x4 acc[4] = {zero, zero, zero, zero};
  const int nchunk = tt + 1;  // 64-s chunks

  uint4 pu[2]; uint2 mu[2]; uint4 vv[NB_][2];
  // prefetch chunk 0
#pragma unroll
  for (int ps = 0; ps < 2; ++ps) {
    const int r = row0 + (ps << 5);
    const size_t pro = ((size_t)((b << 11) + t0 + r)) << 11;
    pu[ps] = *(const uint4*)(&Pb[pro + (part << 3)]);
    mu[ps] = *(const uint2*)(&Mask[pro + (part << 3)]);
#pragma unroll
    for (int n = 0; n < NB_; ++n)
      vv[n][ps] = *(const uint4*)(
          &VT[((size_t)((b * NB_ + n) * C_ + c0 + r)) * T_ + (part << 3)]);
  }
  for (int ck = 0; ck < nchunk; ++ck) {
#pragma unroll
    for (int ps = 0; ps < 2; ++ps) {
      const int r = row0 + (ps << 5);
      const uint4 puv = pu[ps]; const uint2 muv = mu[ps];
      u16 p[8] = {(u16)puv.x, (u16)(puv.x >> 16), (u16)puv.y, (u16)(puv.y >> 16),
                  (u16)puv.z, (u16)(puv.z >> 16), (u16)puv.w, (u16)(puv.w >> 16)};
      u8 mk[8] = {(u8)muv.x, (u8)(muv.x >> 8), (u8)(muv.x >> 16), (u8)(muv.x >> 24),
                  (u8)muv.y, (u8)(muv.y >> 8), (u8)(muv.y >> 16), (u8)(muv.y >> 24)};
#pragma unroll
      for (int n = 0; n < NB_; ++n) {
        uint4 wv;
        wv.x = (unsigned)(((mk[0] >> n) & 1) ? p[0] : 0) |
               ((unsigned)(((mk[1] >> n) & 1) ? p[1] : 0) << 16);
        wv.y = (unsigned)(((mk[2] >> n) & 1) ? p[2] : 0) |
               ((unsigned)(((mk[3] >> n) & 1) ? p[3] : 0) << 16);
        wv.z = (unsigned)(((mk[4] >> n) & 1) ? p[4] : 0) |
               ((unsigned)(((mk[5] >> n) & 1) ? p[5] : 0) << 16);
        wv.w = (unsigned)(((mk[6] >> n) & 1) ? p[6] : 0) |
               ((unsigned)(((mk[7] >> n) & 1) ? p[7] : 0) << 16);
        *(uint4*)(&Ps[n][r][part << 3]) = wv;
        *(uint4*)(&Vs[n][r][part << 3]) = vv[n][ps];
      }
    }
    __syncthreads();
    if (ck + 1 < nchunk) {  // prefetch next chunk (overlaps MFMA)
      const int sB = (ck + 1) << 6;
#pragma unroll
      for (int ps = 0; ps < 2; ++ps) {
        const int r = row0 + (ps << 5);
        const size_t pro = ((size_t)((b << 11) + t0 + r)) << 11;
        pu[ps] = *(const uint4*)(&Pb[pro + sB + (part << 3)]);
        mu[ps] = *(const uint2*)(&Mask[pro + sB + (part << 3)]);
#pragma unroll
        for (int n = 0; n < NB_; ++n)
          vv[n][ps] = *(const uint4*)(
              &VT[((size_t)((b * NB_ + n) * C_ + c0 + r)) * T_ + sB + (part << 3)]);
      }
    }
#pragma unroll
    for (int ks = 0; ks < 2; ++ks) {
#pragma unroll
      for (int n = 0; n < NB_; ++n) {
        short8 af = *(const short8*)(&Ps[n][(wave << 4) + lrow][lk + (ks << 5)]);
#pragma unroll
        for (int cs = 0; cs < 4; ++cs) {
          short8 bf = *(const short8*)(&Vs[n][(cs << 4) + lrow][lk + (ks << 5)]);
          acc[cs] = mfma16x16x32(af, bf, acc[cs]);
        }
      }
    }
    __syncthreads();
  }
  const int tb = t0 + (wave << 4) + ((lane >> 4) << 2);
  const int cbs = c0 + (lane & 15);
#pragma unroll
  for (int cs = 0; cs < 4; ++cs) {
#pragma unroll
    for (int r = 0; r < 4; ++r) {
      Y[(size_t)((b << 11) + tb + r) * C_ + cbs + (cs << 4)] = f2bf(acc[cs][r]);
    }
  }
}

// ---------------------------------------------------------------------------
extern "C" void kernel_launch(void* const* d_in, const int* in_sizes, int n_in,
                              void* d_out, int out_size, void* d_ws,
                              size_t ws_size, hipStream_t stream) {
  (void)in_sizes; (void)n_in; (void)out_size; (void)ws_size;
  const float* a    = (const float*)d_in[0];
  const float* x    = (const float*)d_in[1];
  const float* Wq   = (const float*)d_in[2];
  const float* Wk   = (const float*)d_in[3];
  const float* Wv   = (const float*)d_in[4];
  const float* Wo   = (const float*)d_in[5];
  const float* cosT = (const float*)d_in[6];
  const float* sinT = (const float*)d_in[7];

  char* w = (char*)d_ws;
  u16* Qcat   = (u16*)(w + 0);           // 33.5MB -> first 8.4MB reused as Y
  u16* Kcat   = (u16*)(w + 33554432);    //  8.4MB
  u16* Vraw   = (u16*)(w + 41943040);    // 16.8MB -> reused as bf16 M
  u16* VT     = (u16*)(w + 58720256);    // 16.8MB
  u8*  Mask   = (u8*)(w + 75497472);     //  8.4MB
  float* Rm   = (float*)(w + 83886080);  //  16KB
  float* Rz   = (float*)(w + 83902464);  //  16KB
  u16* Pb     = (u16*)(w + 83918848);    // 16.8MB (end 100,696,064)
  u16* Mb     = Vraw;
  u16* Y      = Qcat;

  const dim3 blk(256);
  gemm_qk<1><<<dim3(32, 64), blk, 0, stream>>>(a, Wq, Qcat, cosT, sinT, 2048, 512);
  gemm_qk<2><<<dim3(8, 64), blk, 0, stream>>>(x, Wk, Kcat, cosT, sinT, 512, 512);
  gemm_hi<1, 0><<<dim3(32, 64), blk, 0, stream>>>(a, Wv, (void*)Vraw, 2048, 512);
  transpose_v_k<<<dim3(2048), blk, 0, stream>>>(Vraw, VT);
  scores_k<<<dim3(528, 2), blk, 0, stream>>>(Qcat, Kcat, Mb, Mask);
  rowstats_k<<<dim3(1024), blk, 0, stream>>>(Mb, Rm, Rz);
  pbuild_k<<<dim3(4096), blk, 0, stream>>>(Mb, Rm, Rz, Pb);
  pv_k<<<dim3(8, 32, 2), blk, 0, stream>>>(Pb, Mask, VT, Y);
  gemm_hi<0, 1><<<dim3(8, 64), blk, 0, stream>>>(Y, Wo, d_out, 512, 512);
}

// Round 12
// 437.373 us; speedup vs baseline: 1.4530x; 1.4530x over previous
//
#include <hip/hip_runtime.h>
#include <math.h>

// ============================================================================
// R12: revert to R8 kernel set (best: 464us) + two surgical pv deltas:
// * pbuild_k precomputes P = f2bf(exp(M-rm)*rz) (R9's proven win) -> pv inner
//   loop is select+pack only.
// * pv_k paired tiles: grid (16,8,2); block y does tiles y AND 31-y ->
//   exactly 66 chunks per block (perfect balance), no atomics/slots/zero.
// R9-R11 lessons: slot-split, balanced-atomics, and heavy prefetch state all
// regressed (occupancy/spill/traffic); keep register footprint small.
// Numerics identical (absmax 0.015625 expected).
// ============================================================================

#define B_ 2
#define T_ 2048
#define C_ 512
#define NB_ 4
#define C2_ 1024  // hi|lo row width for Qcat/Kcat

typedef unsigned short u16;
typedef unsigned char u8;
using short8 = __attribute__((ext_vector_type(8))) short;
using bf16x8 = __attribute__((ext_vector_type(8))) __bf16;
using f32x4  = __attribute__((ext_vector_type(4))) float;

__device__ __forceinline__ float bf2f(u16 u) {
  union { unsigned int i; float f; } v; v.i = ((unsigned int)u) << 16; return v.f;
}
__device__ __forceinline__ u16 f2bf(float f) {  // round-to-nearest-even
  union { float f; unsigned int i; } v; v.f = f;
  unsigned int u = v.i;
  return (u16)((u + 0x7fffu + ((u >> 16) & 1u)) >> 16);
}
__device__ __forceinline__ f32x4 mfma16x16x32(short8 a, short8 b, f32x4 c) {
  return __builtin_amdgcn_mfma_f32_16x16x32_bf16(
      __builtin_bit_cast(bf16x8, a), __builtin_bit_cast(bf16x8, b), c, 0, 0, 0);
}
__device__ __forceinline__ void split8(const float* s, uint4& hi, uint4& lo) {
  u16 h[8], l[8];
#pragma unroll
  for (int j = 0; j < 8; ++j) {
    h[j] = f2bf(s[j]);
    l[j] = f2bf(s[j] - bf2f(h[j]));
  }
  hi.x = h[0] | ((unsigned)h[1] << 16); hi.y = h[2] | ((unsigned)h[3] << 16);
  hi.z = h[4] | ((unsigned)h[5] << 16); hi.w = h[6] | ((unsigned)h[7] << 16);
  lo.x = l[0] | ((unsigned)l[1] << 16); lo.y = l[2] | ((unsigned)l[3] << 16);
  lo.z = l[4] | ((unsigned)l[5] << 16); lo.w = l[6] | ((unsigned)l[7] << 16);
}

// ---------------------------------------------------------------------------
// Split-precision 64x64 GEMM with fused RoPE epilogue (R8 version).
// MODE 1: +1/sqrt(C) scale -> Qcat (B,NB,T,[hi512|lo512]).
// MODE 2: -> Kcat (B*T,[hi512|lo512]).
// ---------------------------------------------------------------------------
template <int MODE>
__global__ __launch_bounds__(256) void gemm_qk(const float* __restrict__ A,
                                               const float* __restrict__ W,
                                               u16* __restrict__ out,
                                               const float* __restrict__ cosT,
                                               const float* __restrict__ sinT,
                                               const int N, const int K) {
  __shared__ u16 Ah[64][32], Al[64][32];
  __shared__ u16 Bh[64][32], Bl[64][32];  // [n][k]
  const int tid = threadIdx.x;
  const int wave = tid >> 6, lane = tid & 63;
  const int m0 = blockIdx.y << 6, n0 = blockIdx.x << 6;
  const f32x4 zero = {0.f, 0.f, 0.f, 0.f};
  f32x4 acc[4] = {zero, zero, zero, zero};
  const int srow = tid >> 2, koff = (tid & 3) << 3;  // linear LDS staging
  const int lrow = lane & 15, lk = (lane >> 4) << 3;
  for (int kk = 0; kk < K; kk += 32) {
    float av[8];
    *(float4*)(av) = *(const float4*)(&A[(size_t)(m0 + srow) * K + kk + koff]);
    *(float4*)(av + 4) =
        *(const float4*)(&A[(size_t)(m0 + srow) * K + kk + koff + 4]);
    uint4 hi, lo;
    split8(av, hi, lo);
    *(uint4*)(&Ah[srow][koff]) = hi;
    *(uint4*)(&Al[srow][koff]) = lo;
    float wv[8];
#pragma unroll
    for (int j = 0; j < 8; ++j)
      wv[j] = W[(size_t)(kk + koff + j) * N + n0 + srow];
    split8(wv, hi, lo);
    *(uint4*)(&Bh[srow][koff]) = hi;
    *(uint4*)(&Bl[srow][koff]) = lo;
    __syncthreads();
    short8 ah = *(const short8*)(&Ah[(wave << 4) + lrow][lk]);
    short8 al = *(const short8*)(&Al[(wave << 4) + lrow][lk]);
#pragma unroll
    for (int ns = 0; ns < 4; ++ns) {
      short8 bh = *(const short8*)(&Bh[(ns << 4) + lrow][lk]);
      short8 bl = *(const short8*)(&Bl[(ns << 4) + lrow][lk]);
      acc[ns] = mfma16x16x32(ah, bh, acc[ns]);
      acc[ns] = mfma16x16x32(al, bh, acc[ns]);
      acc[ns] = mfma16x16x32(ah, bl, acc[ns]);
    }
    __syncthreads();
  }
  const int r0 = m0 + (wave << 4) + ((lane >> 4) << 2);
  const int cb = n0 + (lane & 15);
#pragma unroll
  for (int ns = 0; ns < 4; ++ns) {
#pragma unroll
    for (int r = 0; r < 4; ++r) {
      const int rg = r0 + r;
      const int cg = cb + (ns << 4);
      float v = acc[ns][r];
      float pv = __shfl_xor(v, 1);  // partner column of the RoPE pair
      const int t = rg & (T_ - 1);
      const int c = (MODE == 1) ? (cg & (C_ - 1)) : cg;
      const int i = c >> 1;
      const float cf = cosT[(t << 8) + i];
      const float sf = sinT[(t << 8) + i];
      float x1 = (lane & 1) ? pv : v;
      float x2 = (lane & 1) ? v : pv;
      float y = (lane & 1) ? (x1 * sf + x2 * cf) : (x1 * cf - x2 * sf);
      if (MODE == 1) y *= 0.044194173824159216f;  // 1/sqrt(512)
      const u16 hi = f2bf(y);
      const u16 lo = f2bf(y - bf2f(hi));
      size_t rowoff;
      if (MODE == 1) {
        const int b = rg >> 11, n = cg >> 9;
        rowoff = ((size_t)((b * NB_ + n) * T_ + t)) * C2_;
      } else {
        rowoff = (size_t)rg * C2_;
      }
      out[rowoff + c] = hi;
      out[rowoff + C_ + c] = lo;
    }
  }
}

// ---------------------------------------------------------------------------
// Plain hi-only GEMM: A f32 (AF32=1) or bf16, W f32; out bf16 or f32 (OF32).
// ---------------------------------------------------------------------------
template <int AF32, int OF32>
__global__ __launch_bounds__(256) void gemm_hi(const void* __restrict__ Ap,
                                               const float* __restrict__ W,
                                               void* __restrict__ outp,
                                               const int N, const int K) {
  __shared__ u16 As[64][32];
  __shared__ u16 Bs[64][32];
  const int tid = threadIdx.x;
  const int wave = tid >> 6, lane = tid & 63;
  const int m0 = blockIdx.y << 6, n0 = blockIdx.x << 6;
  const f32x4 zero = {0.f, 0.f, 0.f, 0.f};
  f32x4 acc[4] = {zero, zero, zero, zero};
  const int srow = tid >> 2, koff = (tid & 3) << 3;  // linear LDS staging
  const int lrow = lane & 15, lk = (lane >> 4) << 3;
  for (int kk = 0; kk < K; kk += 32) {
    if (AF32) {
      const float* A = (const float*)Ap;
      float av[8];
      *(float4*)(av) = *(const float4*)(&A[(size_t)(m0 + srow) * K + kk + koff]);
      *(float4*)(av + 4) =
          *(const float4*)(&A[(size_t)(m0 + srow) * K + kk + koff + 4]);
      uint4 hi;
      hi.x = f2bf(av[0]) | ((unsigned)f2bf(av[1]) << 16);
      hi.y = f2bf(av[2]) | ((unsigned)f2bf(av[3]) << 16);
      hi.z = f2bf(av[4]) | ((unsigned)f2bf(av[5]) << 16);
      hi.w = f2bf(av[6]) | ((unsigned)f2bf(av[7]) << 16);
      *(uint4*)(&As[srow][koff]) = hi;
    } else {
      const u16* A = (const u16*)Ap;
      *(uint4*)(&As[srow][koff]) =
          *(const uint4*)(&A[(size_t)(m0 + srow) * K + kk + koff]);
    }
    uint4 hi;
    {
      float w[8];
#pragma unroll
      for (int j = 0; j < 8; ++j)
        w[j] = W[(size_t)(kk + koff + j) * N + n0 + srow];
      hi.x = f2bf(w[0]) | ((unsigned)f2bf(w[1]) << 16);
      hi.y = f2bf(w[2]) | ((unsigned)f2bf(w[3]) << 16);
      hi.z = f2bf(w[4]) | ((unsigned)f2bf(w[5]) << 16);
      hi.w = f2bf(w[6]) | ((unsigned)f2bf(w[7]) << 16);
    }
    *(uint4*)(&Bs[srow][koff]) = hi;
    __syncthreads();
    short8 af = *(const short8*)(&As[(wave << 4) + lrow][lk]);
#pragma unroll
    for (int ns = 0; ns < 4; ++ns) {
      short8 bf = *(const short8*)(&Bs[(ns << 4) + lrow][lk]);
      acc[ns] = mfma16x16x32(af, bf, acc[ns]);
    }
    __syncthreads();
  }
  const int r0 = m0 + (wave << 4) + ((lane >> 4) << 2);
  const int cb = n0 + (lane & 15);
#pragma unroll
  for (int ns = 0; ns < 4; ++ns) {
#pragma unroll
    for (int r = 0; r < 4; ++r) {
      const size_t idx = (size_t)(r0 + r) * N + cb + (ns << 4);
      if (OF32) ((float*)outp)[idx] = acc[ns][r];
      else ((u16*)outp)[idx] = f2bf(acc[ns][r]);
    }
  }
}

// ---------------------------------------------------------------------------
// Vraw (B,T,NB*C) bf16 -> VT (B,NB,C,T) tiled transpose, 64x64 tiles.
// ---------------------------------------------------------------------------
__global__ __launch_bounds__(256) void transpose_v_k(const u16* __restrict__ Vraw,
                                                     u16* __restrict__ VT) {
  const int bid = blockIdx.x;
  const int ct = bid & 7;
  const int ttile = (bid >> 3) & 31;
  const int n = (bid >> 8) & 3;
  const int b = bid >> 10;
  __shared__ u16 tile[64][68];
  const int tid = threadIdx.x;
  const int rr = tid >> 4;
  const int cc = (tid & 15) << 2;
  const int t0 = ttile << 6, c0 = ct << 6;
#pragma unroll
  for (int it = 0; it < 4; ++it) {
    const int r = (it << 4) + rr;
    *(ushort4*)(&tile[r][cc]) = *(const ushort4*)(
        &Vraw[((size_t)((b << 11) + t0 + r)) * (NB_ * C_) + n * C_ + c0 + cc]);
  }
  __syncthreads();
#pragma unroll
  for (int it = 0; it < 4; ++it) {
    const int c = (it << 4) + rr;
    ushort4 w;
    w.x = tile[cc + 0][c]; w.y = tile[cc + 1][c];
    w.z = tile[cc + 2][c]; w.w = tile[cc + 3][c];
    *(ushort4*)(&VT[((size_t)((b * NB_ + n) * C_ + c0 + c)) * T_ + t0 + cc]) = w;
  }
}

// ---------------------------------------------------------------------------
// Scores (R8 version): per lower-tri 64x64 (t,s) tile (triangular grid),
// 4 branches, fused split segments (40KB LDS). Writes M (bf16), Mask (u8).
// ---------------------------------------------------------------------------
__global__ __launch_bounds__(256) void scores_k(const u16* __restrict__ Qcat,
                                                const u16* __restrict__ Kcat,
                                                u16* __restrict__ Mout,
                                                u8* __restrict__ Mask) {
  const int tri = blockIdx.x;
  int tt = (int)((sqrtf(8.f * (float)tri + 1.f) - 1.f) * 0.5f);
  while ((tt + 1) * (tt + 2) / 2 <= tri) ++tt;
  while (tt * (tt + 1) / 2 > tri) --tt;
  const int ss = tri - tt * (tt + 1) / 2;
  const int b = blockIdx.y;
  __shared__ u16 Qh[NB_][64][32], Ql[NB_][64][32];
  __shared__ u16 Kh[64][32], Kl[64][32];
  const int tid = threadIdx.x;
  const int wave = tid >> 6, lane = tid & 63;
  const int t0 = tt << 6, s0 = ss << 6;
  const f32x4 zero = {0.f, 0.f, 0.f, 0.f};
  f32x4 acc[NB_][4];
  for (int n = 0; n < NB_; ++n)
    for (int j = 0; j < 4; ++j) acc[n][j] = zero;
  const int srow = tid >> 2, koff = (tid & 3) << 3;  // linear LDS staging
  const int lrow = lane & 15, lk = (lane >> 4) << 3;
  for (int kk = 0; kk < C_; kk += 32) {
#pragma unroll
    for (int n = 0; n < NB_; ++n) {
      const size_t qb =
          ((size_t)((b * NB_ + n) * T_ + t0 + srow)) * C2_ + kk + koff;
      *(uint4*)(&Qh[n][srow][koff]) = *(const uint4*)(&Qcat[qb]);
      *(uint4*)(&Ql[n][srow][koff]) = *(const uint4*)(&Qcat[qb + C_]);
    }
    const size_t kb = ((size_t)((b << 11) + s0 + srow)) * C2_ + kk + koff;
    *(uint4*)(&Kh[srow][koff]) = *(const uint4*)(&Kcat[kb]);
    *(uint4*)(&Kl[srow][koff]) = *(const uint4*)(&Kcat[kb + C_]);
    __syncthreads();
    short8 qh[NB_], ql[NB_];
#pragma unroll
    for (int n = 0; n < NB_; ++n) {
      qh[n] = *(const short8*)(&Qh[n][(wave << 4) + lrow][lk]);
      ql[n] = *(const short8*)(&Ql[n][(wave << 4) + lrow][lk]);
    }
#pragma unroll
    for (int ns = 0; ns < 4; ++ns) {
      short8 kh = *(const short8*)(&Kh[(ns << 4) + lrow][lk]);
      short8 kl = *(const short8*)(&Kl[(ns << 4) + lrow][lk]);
#pragma unroll
      for (int n = 0; n < NB_; ++n) {
        acc[n][ns] = mfma16x16x32(qh[n], kh, acc[n][ns]);
        acc[n][ns] = mfma16x16x32(ql[n], kh, acc[n][ns]);
        acc[n][ns] = mfma16x16x32(qh[n], kl, acc[n][ns]);
      }
    }
    __syncthreads();
  }
  const int tb = t0 + (wave << 4) + ((lane >> 4) << 2);
  const int sb = s0 + (lane & 15);
#pragma unroll
  for (int ns = 0; ns < 4; ++ns) {
#pragma unroll
    for (int r = 0; r < 4; ++r) {
      const int t = tb + r, s = sb + (ns << 4);
      float a0 = acc[0][ns][r], a1 = acc[1][ns][r];
      float a2 = acc[2][ns][r], a3 = acc[3][ns][r];
      float m = fmaxf(fmaxf(a0, a1), fmaxf(a2, a3));
      u8 msk = (u8)((a0 == m) | ((a1 == m) << 1) | ((a2 == m) << 2) |
                    ((a3 == m) << 3));
      if (s > t) { m = -__builtin_inff(); msk = 0; }
      const size_t idx = (size_t)b * T_ * T_ + (size_t)t * T_ + s;
      Mout[idx] = f2bf(m);
      Mask[idx] = msk;
    }
  }
}

// ---------------------------------------------------------------------------
// Per-row softmax stats from bf16 M: rowmax, 1/sum(exp). One wave per (b,t).
// ---------------------------------------------------------------------------
__global__ __launch_bounds__(256) void rowstats_k(const u16* __restrict__ Mb,
                                                  float* __restrict__ Rm,
                                                  float* __restrict__ Rz) {
  const int r = (blockIdx.x << 2) + (threadIdx.x >> 6);
  const int lane = threadIdx.x & 63;
  const int b = r >> 11, t = r & (T_ - 1);
  const u16* row = Mb + (size_t)b * T_ * T_ + (size_t)t * T_;
  float m = -__builtin_inff();
  for (int s = lane; s <= t; s += 64) m = fmaxf(m, bf2f(row[s]));
#pragma unroll
  for (int off = 32; off; off >>= 1) m = fmaxf(m, __shfl_xor(m, off));
  float z = 0.f;
  for (int s = lane; s <= t; s += 64) z += expf(bf2f(row[s]) - m);
#pragma unroll
  for (int off = 32; off; off >>= 1) z += __shfl_xor(z, off);
  if (lane == 0) { Rm[r] = m; Rz[r] = 1.f / z; }
}

// ---------------------------------------------------------------------------
// P-build: P[b,t,s] = f2bf(exp(M - rm) * rz). One block per (b,t) row.
// ---------------------------------------------------------------------------
__global__ __launch_bounds__(256) void pbuild_k(const u16* __restrict__ Mb,
                                                const float* __restrict__ Rm,
                                                const float* __restrict__ Rz,
                                                u16* __restrict__ Pb) {
  const int r = blockIdx.x;
  const float rm = Rm[r], rz = Rz[r];
  const size_t off = ((size_t)r << 11) + (threadIdx.x << 3);
  ushort4 m0 = *(const ushort4*)(&Mb[off]);
  ushort4 m1 = *(const ushort4*)(&Mb[off + 4]);
  u16 o[8];
  o[0] = f2bf(expf(bf2f(m0.x) - rm) * rz);
  o[1] = f2bf(expf(bf2f(m0.y) - rm) * rz);
  o[2] = f2bf(expf(bf2f(m0.z) - rm) * rz);
  o[3] = f2bf(expf(bf2f(m0.w) - rm) * rz);
  o[4] = f2bf(expf(bf2f(m1.x) - rm) * rz);
  o[5] = f2bf(expf(bf2f(m1.y) - rm) * rz);
  o[6] = f2bf(expf(bf2f(m1.z) - rm) * rz);
  o[7] = f2bf(expf(bf2f(m1.w) - rm) * rz);
  uint4 w;
  w.x = o[0] | ((unsigned)o[1] << 16); w.y = o[2] | ((unsigned)o[3] << 16);
  w.z = o[4] | ((unsigned)o[5] << 16); w.w = o[6] | ((unsigned)o[7] << 16);
  *(uint4*)(&Pb[off]) = w;
}

// ---------------------------------------------------------------------------
// Routed PV, paired tiles: grid (16,8,2); block y handles tile tt=y then
// tile tt=31-y -> exactly 66 chunks/block (perfect balance, no atomics).
// P precomputed; one-chunk register prefetch within each half (R8 staging
// pattern: 32-s chunks, linear LDS writes, 32KB LDS).
// ---------------------------------------------------------------------------
__global__ __launch_bounds__(256) void pv_k(const u16* __restrict__ Pb,
                                            const u8* __restrict__ Mask,
                                            const u16* __restrict__ VT,
                                            u16* __restrict__ Y) {
  const int ypair = blockIdx.x, cblk = blockIdx.y, b = blockIdx.z;
  const int c0 = cblk << 6;
  __shared__ u16 Ps[NB_][64][32];
  __shared__ u16 Vs[NB_][64][32];
  const int tid = threadIdx.x;
  const int wave = tid >> 6, lane = tid & 63;
  const int prow = tid >> 2, soff = (tid & 3) << 3;  // linear LDS staging
  const int lrow = lane & 15, lk = (lane >> 4) << 3;
  const f32x4 zero = {0.f, 0.f, 0.f, 0.f};
  const size_t vrow_base[NB_] = {
      ((size_t)((b * NB_ + 0) * C_ + c0 + prow)) * T_,
      ((size_t)((b * NB_ + 1) * C_ + c0 + prow)) * T_,
      ((size_t)((b * NB_ + 2) * C_ + c0 + prow)) * T_,
      ((size_t)((b * NB_ + 3) * C_ + c0 + prow)) * T_};

  for (int half = 0; half < 2; ++half) {
    const int tt = half ? (31 - ypair) : ypair;
    const int t0 = tt << 6;
    const int nchunk = (tt + 1) << 1;
    const size_t pro = ((size_t)((b << 11) + t0 + prow)) << 11;
    f32x4 acc[4] = {zero, zero, zero, zero};
    uint4 pu; uint2 mk2; uint4 vv[NB_];
    // prefetch chunk 0
    pu = *(const uint4*)(&Pb[pro + soff]);
    mk2 = *(const uint2*)(&Mask[pro + soff]);
#pragma unroll
    for (int n = 0; n < NB_; ++n)
      vv[n] = *(const uint4*)(&VT[vrow_base[n] + soff]);
    for (int ck = 0; ck < nchunk; ++ck) {
      u16 p[8] = {(u16)pu.x, (u16)(pu.x >> 16), (u16)pu.y, (u16)(pu.y >> 16),
                  (u16)pu.z, (u16)(pu.z >> 16), (u16)pu.w, (u16)(pu.w >> 16)};
      u8 mk[8] = {(u8)mk2.x, (u8)(mk2.x >> 8), (u8)(mk2.x >> 16),
                  (u8)(mk2.x >> 24), (u8)mk2.y, (u8)(mk2.y >> 8),
                  (u8)(mk2.y >> 16), (u8)(mk2.y >> 24)};
#pragma unroll
      for (int n = 0; n < NB_; ++n) {
        uint4 wv;
        wv.x = (unsigned)(((mk[0] >> n) & 1) ? p[0] : 0) |
               ((unsigned)(((mk[1] >> n) & 1) ? p[1] : 0) << 16);
        wv.y = (unsigned)(((mk[2] >> n) & 1) ? p[2] : 0) |
               ((unsigned)(((mk[3] >> n) & 1) ? p[3] : 0) << 16);
        wv.z = (unsigned)(((mk[4] >> n) & 1) ? p[4] : 0) |
               ((unsigned)(((mk[5] >> n) & 1) ? p[5] : 0) << 16);
        wv.w = (unsigned)(((mk[6] >> n) & 1) ? p[6] : 0) |
               ((unsigned)(((mk[7] >> n) & 1) ? p[7] : 0) << 16);
        *(uint4*)(&Ps[n][prow][soff]) = wv;
        *(uint4*)(&Vs[n][prow][soff]) = vv[n];
      }
      __syncthreads();
      if (ck + 1 < nchunk) {  // prefetch next chunk (overlaps MFMA)
        const int sB = (ck + 1) << 5;
        pu = *(const uint4*)(&Pb[pro + sB + soff]);
        mk2 = *(const uint2*)(&Mask[pro + sB + soff]);
#pragma unroll
        for (int n = 0; n < NB_; ++n)
          vv[n] = *(const uint4*)(&VT[vrow_base[n] + sB + soff]);
      }
#pragma unroll
      for (int n = 0; n < NB_; ++n) {
        short8 af = *(const short8*)(&Ps[n][(wave << 4) + lrow][lk]);
#pragma unroll
        for (int cs = 0; cs < 4; ++cs) {
          short8 bf = *(const short8*)(&Vs[n][(cs << 4) + lrow][lk]);
          acc[cs] = mfma16x16x32(af, bf, acc[cs]);
        }
      }
      __syncthreads();
    }
    const int tb = t0 + (wave << 4) + ((lane >> 4) << 2);
    const int cbs = c0 + (lane & 15);
#pragma unroll
    for (int cs = 0; cs < 4; ++cs) {
#pragma unroll
      for (int r = 0; r < 4; ++r) {
        Y[(size_t)((b << 11) + tb + r) * C_ + cbs + (cs << 4)] =
            f2bf(acc[cs][r]);
      }
    }
  }
}

// ---------------------------------------------------------------------------
extern "C" void kernel_launch(void* const* d_in, const int* in_sizes, int n_in,
                              void* d_out, int out_size, void* d_ws,
                              size_t ws_size, hipStream_t stream) {
  (void)in_sizes; (void)n_in; (void)out_size; (void)ws_size;
  const float* a    = (const float*)d_in[0];
  const float* x    = (const float*)d_in[1];
  const float* Wq   = (const float*)d_in[2];
  const float* Wk   = (const float*)d_in[3];
  const float* Wv   = (const float*)d_in[4];
  const float* Wo   = (const float*)d_in[5];
  const float* cosT = (const float*)d_in[6];
  const float* sinT = (const float*)d_in[7];

  char* w = (char*)d_ws;
  u16* Qcat   = (u16*)(w + 0);           // 33.5MB -> first 4.2MB reused as Y
  u16* Kcat   = (u16*)(w + 33554432);    //  8.4MB
  u16* Vraw   = (u16*)(w + 41943040);    // 16.8MB -> reused as bf16 M
  u16* VT     = (u16*)(w + 58720256);    // 16.8MB
  u8*  Mask   = (u8*)(w + 75497472);     //  8.4MB
  float* Rm   = (float*)(w + 83886080);  //  16KB
  float* Rz   = (float*)(w + 83902464);  //  16KB
  u16* Pb     = (u16*)(w + 83918848);    // 16.8MB (end 100,696,064)
  u16* Mb     = Vraw;
  u16* Y      = Qcat;

  const dim3 blk(256);
  gemm_qk<1><<<dim3(32, 64), blk, 0, stream>>>(a, Wq, Qcat, cosT, sinT, 2048, 512);
  gemm_qk<2><<<dim3(8, 64), blk, 0, stream>>>(x, Wk, Kcat, cosT, sinT, 512, 512);
  gemm_hi<1, 0><<<dim3(32, 64), blk, 0, stream>>>(a, Wv, (void*)Vraw, 2048, 512);
  transpose_v_k<<<dim3(2048), blk, 0, stream>>>(Vraw, VT);
  scores_k<<<dim3(528, 2), blk, 0, stream>>>(Qcat, Kcat, Mb, Mask);
  rowstats_k<<<dim3(1024), blk, 0, stream>>>(Mb, Rm, Rz);
  pbuild_k<<<dim3(4096), blk, 0, stream>>>(Mb, Rm, Rz, Pb);
  pv_k<<<dim3(16, 8, 2), blk, 0, stream>>>(Pb, Mask, VT, Y);
  gemm_hi<0, 1><<<dim3(8, 64), blk, 0, stream>>>(Y, Wo, d_out, 512, 512);
}